// Round 13
// baseline (296.099 us; speedup 1.0000x reference)
//
#include <hip/hip_runtime.h>

#define NN 100000
#define NE 400000
#define FD 128
#define SCAN_B 1024

typedef __attribute__((ext_vector_type(8))) short bf16x8;
typedef __attribute__((ext_vector_type(4))) float f32x4;

__device__ inline unsigned short f2bf(float f) {
    unsigned u = __float_as_uint(f);
    unsigned r = u + 0x7fff + ((u >> 16) & 1);
    return (unsigned short)(r >> 16);
}
__device__ inline unsigned mulbf2(unsigned a, unsigned c) {
    float a0 = __uint_as_float(a << 16), a1 = __uint_as_float(a & 0xffff0000u);
    float c0 = __uint_as_float(c << 16), c1 = __uint_as_float(c & 0xffff0000u);
    unsigned r0 = f2bf(a0 * c0);
    unsigned r1 = f2bf(a1 * c1);
    return r0 | (r1 << 16);
}
// XOR-swizzled z index (shorts). granule = 8 shorts (16B).
__device__ inline int zi(int row, int col) {
    return row * 128 + (((col >> 3) ^ (row & 7)) << 3) + (col & 7);
}

// ---------------- degree / norm / CSR ----------------
__global__ void k_deg_count(const int* __restrict__ key, int* __restrict__ deg) {
    int e = blockIdx.x * 256 + threadIdx.x;
    if (e < NE) atomicAdd(&deg[key[e]], 1);
}
// scan within 1024-blocks; also emits norm = rsqrt(deg+1)
__global__ __launch_bounds__(SCAN_B) void k_scan1(const int* __restrict__ deg,
                                                  int* __restrict__ off,
                                                  int* __restrict__ bsum,
                                                  float* __restrict__ norm) {
    __shared__ int s[SCAN_B];
    int t = threadIdx.x, g = blockIdx.x * SCAN_B + t;
    int d0 = (g < NN) ? deg[g] : 0;
    if (g < NN) norm[g] = rsqrtf((float)(d0 + 1));
    s[t] = d0;
    __syncthreads();
    for (int d = 1; d < SCAN_B; d <<= 1) {
        int add = (t >= d) ? s[t - d] : 0;
        __syncthreads();
        s[t] += add;
        __syncthreads();
    }
    if (g < NN) off[g + 1] = s[t];
    if (t == SCAN_B - 1) bsum[blockIdx.x] = s[t];
}
// wave-parallel exclusive scan of <=128 block sums (1 block, 64 threads)
__global__ void k_scan2(int* __restrict__ bsum, int nb) {
    int l = threadIdx.x;
    int v0 = (l < nb) ? bsum[l] : 0;
    int v1 = (64 + l < nb) ? bsum[64 + l] : 0;
    int a = v0;
    for (int d = 1; d < 64; d <<= 1) {
        int t = __shfl_up(a, d, 64);
        if (l >= d) a += t;
    }
    int tot0 = __shfl(a, 63, 64);
    int b = v1;
    for (int d = 1; d < 64; d <<= 1) {
        int t = __shfl_up(b, d, 64);
        if (l >= d) b += t;
    }
    if (l < nb) bsum[l] = a - v0;                 // exclusive
    if (64 + l < nb) bsum[64 + l] = tot0 + b - v1;
}
// finalize off; also emit cur = off (cursor copy)
__global__ void k_scan3(int* __restrict__ off, const int* __restrict__ bsum,
                        int* __restrict__ cur) {
    int g = blockIdx.x * 256 + threadIdx.x;
    if (g == 0) { off[0] = 0; cur[0] = 0; }
    if (g < NN) {
        int v = off[g + 1] + bsum[g / SCAN_B];
        off[g + 1] = v;
        cur[g + 1] = v;
    }
}
__global__ void k_fill(const int* __restrict__ src, const int* __restrict__ dst,
                       int* __restrict__ cur, int* __restrict__ csr) {
    int e = blockIdx.x * 256 + threadIdx.x;
    if (e < NE) {
        int p = atomicAdd(&cur[dst[e]], 1);
        csr[p] = src[e];
    }
}

// ---------------- pre-scale: xs = norm * x (bf16) ----------------
__global__ __launch_bounds__(256) void k_scale(const float* __restrict__ x,
        const float* __restrict__ norm, unsigned short* __restrict__ xs) {
    int i = blockIdx.x * 256 + threadIdx.x;   // float4 index
    if (i >= NN * (FD / 4)) return;
    int v = i >> 5;
    float nv = norm[v];
    float4 a = ((const float4*)x)[i];
    unsigned lo = f2bf(nv * a.x) | ((unsigned)f2bf(nv * a.y) << 16);
    unsigned hi = f2bf(nv * a.z) | ((unsigned)f2bf(nv * a.w) << 16);
    ((uint2*)xs)[i] = make_uint2(lo, hi);
}

// ---------------- propagation (bf16 storage, f32 accumulate) ----------------
template <bool LAST>
__global__ __launch_bounds__(256) void k_prop(const unsigned short* __restrict__ Gin,
        const int* __restrict__ off, const int* __restrict__ csr,
        const float* __restrict__ norm, unsigned short* __restrict__ Gout) {
    int t = blockIdx.x * 256 + threadIdx.x;
    int v = t >> 5, lane = t & 31;
    float nv = norm[v];
    uint2 g = ((const uint2*)(Gin + (size_t)v * FD))[lane];
    float ax = __uint_as_float(g.x << 16), ay = __uint_as_float(g.x & 0xffff0000u);
    float az = __uint_as_float(g.y << 16), aw = __uint_as_float(g.y & 0xffff0000u);
    int j = off[v], j1 = off[v + 1];
    for (; j + 3 < j1; j += 4) {
        int s0 = csr[j], s1 = csr[j + 1], s2 = csr[j + 2], s3 = csr[j + 3];
        uint2 b0 = ((const uint2*)(Gin + (size_t)s0 * FD))[lane];
        uint2 b1 = ((const uint2*)(Gin + (size_t)s1 * FD))[lane];
        uint2 b2 = ((const uint2*)(Gin + (size_t)s2 * FD))[lane];
        uint2 b3 = ((const uint2*)(Gin + (size_t)s3 * FD))[lane];
        ax += __uint_as_float(b0.x << 16) + __uint_as_float(b1.x << 16)
            + __uint_as_float(b2.x << 16) + __uint_as_float(b3.x << 16);
        ay += __uint_as_float(b0.x & 0xffff0000u) + __uint_as_float(b1.x & 0xffff0000u)
            + __uint_as_float(b2.x & 0xffff0000u) + __uint_as_float(b3.x & 0xffff0000u);
        az += __uint_as_float(b0.y << 16) + __uint_as_float(b1.y << 16)
            + __uint_as_float(b2.y << 16) + __uint_as_float(b3.y << 16);
        aw += __uint_as_float(b0.y & 0xffff0000u) + __uint_as_float(b1.y & 0xffff0000u)
            + __uint_as_float(b2.y & 0xffff0000u) + __uint_as_float(b3.y & 0xffff0000u);
    }
    for (; j < j1; j++) {
        int s0 = csr[j];
        uint2 b0 = ((const uint2*)(Gin + (size_t)s0 * FD))[lane];
        ax += __uint_as_float(b0.x << 16);
        ay += __uint_as_float(b0.x & 0xffff0000u);
        az += __uint_as_float(b0.y << 16);
        aw += __uint_as_float(b0.y & 0xffff0000u);
    }
    float sc = LAST ? nv : nv * nv;
    unsigned lo = f2bf(sc * ax) | ((unsigned)f2bf(sc * ay) << 16);
    unsigned hi = f2bf(sc * az) | ((unsigned)f2bf(sc * aw) << 16);
    ((uint2*)(Gout + (size_t)v * FD))[lane] = make_uint2(lo, hi);
}

// ---------------- weight packing ----------------
__global__ void k_pack_w(const float* __restrict__ Wsg, const float* __restrict__ W1,
                         const float* __restrict__ W2, uint4* __restrict__ wp) {
    int t = blockIdx.x * 256 + threadIdx.x;
    int wsel = t >> 11, r = t & 2047;
    const float* W = wsel == 0 ? Wsg : (wsel == 1 ? W1 : W2);
    int frag = r >> 6, l = r & 63;
    int nt = frag >> 2, kb = frag & 3;
    int col = 16 * nt + (l & 15);
    int k0 = 32 * kb + 8 * (l >> 4);
    unsigned q[4];
#pragma unroll
    for (int j = 0; j < 4; j++) {
        unsigned lo = f2bf(W[(size_t)(k0 + 2 * j) * FD + col]);
        unsigned hi = f2bf(W[(size_t)(k0 + 2 * j + 1) * FD + col]);
        q[j] = lo | (hi << 16);
    }
    wp[t] = make_uint4(q[0], q[1], q[2], q[3]);
}

// ---------------- SGConv linear via MFMA (32 KB swizzled LDS) ----------------
__global__ __launch_bounds__(256, 4) void k_sgconv_mfma(const unsigned short* __restrict__ hin,
        const uint4* __restrict__ wp, const float* __restrict__ bsg,
        unsigned short* __restrict__ hout) {
    __shared__ unsigned short z[128 * 128];
    int tid = threadIdx.x;
    int row0 = blockIdx.x * 128;
#pragma unroll
    for (int it = 0; it < 8; it++) {
        int idx = it * 256 + tid;
        int r = idx >> 4, c = idx & 15;
        uint4 v = make_uint4(0, 0, 0, 0);
        if (row0 + r < NN) v = *(const uint4*)(hin + (size_t)(row0 + r) * FD + c * 8);
        *(uint4*)&z[zi(r, c * 8)] = v;
    }
    __syncthreads();

    int l = tid & 63, w = tid >> 6;
    f32x4 acc[2][8];
#pragma unroll
    for (int mt = 0; mt < 2; mt++)
#pragma unroll
        for (int nt = 0; nt < 8; nt++) acc[mt][nt] = (f32x4){0, 0, 0, 0};

#pragma unroll
    for (int kb = 0; kb < 4; kb++) {
        bf16x8 af[2];
#pragma unroll
        for (int mt = 0; mt < 2; mt++)
            af[mt] = *(const bf16x8*)&z[zi(w * 32 + mt * 16 + (l & 15), kb * 32 + (l >> 4) * 8)];
#pragma unroll
        for (int nt = 0; nt < 8; nt++) {
            bf16x8 wf = *(const bf16x8*)&wp[(nt * 4 + kb) * 64 + l];
#pragma unroll
            for (int mt = 0; mt < 2; mt++)
                acc[mt][nt] = __builtin_amdgcn_mfma_f32_16x16x32_bf16(af[mt], wf, acc[mt][nt], 0, 0, 0);
        }
    }
#pragma unroll
    for (int mt = 0; mt < 2; mt++)
#pragma unroll
        for (int nt = 0; nt < 8; nt++) {
            float bv = bsg[16 * nt + (l & 15)];
#pragma unroll
            for (int r = 0; r < 4; r++)
                z[zi(w * 32 + mt * 16 + (l >> 4) * 4 + r, 16 * nt + (l & 15))] =
                    f2bf(acc[mt][nt][r] + bv);
        }
    __syncthreads();
#pragma unroll
    for (int it = 0; it < 8; it++) {
        int idx = it * 256 + tid;
        int r = idx >> 4, c = idx & 15;
        if (row0 + r < NN)
            *(uint4*)(hout + (size_t)(row0 + r) * FD + c * 8) = *(const uint4*)&z[zi(r, c * 8)];
    }
}

// ---------------- predict MLP via MFMA (pos+neg) ----------------
// R11 codegen with ONE change: z addressing ZS=136 pad -> zi() swizzle,
// LDS 34.8 -> 32 KB => 5 blocks/CU (20 waves/CU). Staging stays inline per-q.
__global__ __launch_bounds__(256, 4) void k_predict_mfma(const unsigned short* __restrict__ h,
        const int* __restrict__ srcA, const int* __restrict__ dstA,
        const int* __restrict__ srcB, const int* __restrict__ dstB,
        const uint4* __restrict__ w1p, const uint4* __restrict__ w2p,
        const float* __restrict__ b1, const float* __restrict__ b2,
        const float* __restrict__ W3, const float* __restrict__ b3,
        float* __restrict__ out) {
    __shared__ unsigned short z[128 * 128];   // 32 KB, XOR-swizzled
    int tid = threadIdx.x;
    int b = blockIdx.x;
    int half = b >= 3125;
    int eb = (b - (half ? 3125 : 0)) * 128;
    const int* S = half ? srcB : srcA;
    const int* D = half ? dstB : dstA;
    int outbase = half ? NE : 0;

    // stage z = h[s]*h[d] (bf16); 4 threads x 64B-chunks per edge, 2 iters
#pragma unroll
    for (int it = 0; it < 2; it++) {
        int e = (tid >> 2) + 64 * it;
        int p = tid & 3;
        int s = S[eb + e], d = D[eb + e];
        const uint4* hs = (const uint4*)(h + (size_t)s * FD + p * 32);
        const uint4* hd = (const uint4*)(h + (size_t)d * FD + p * 32);
#pragma unroll
        for (int q = 0; q < 4; q++) {
            uint4 a = hs[q], c = hd[q];
            uint4 r;
            r.x = mulbf2(a.x, c.x);
            r.y = mulbf2(a.y, c.y);
            r.z = mulbf2(a.z, c.z);
            r.w = mulbf2(a.w, c.w);
            *(uint4*)&z[zi(e, p * 32 + q * 8)] = r;
        }
    }
    __syncthreads();

    int l = tid & 63, w = tid >> 6;   // wave w owns rows w*32 .. w*32+31
    f32x4 acc[2][8];
#pragma unroll
    for (int mt = 0; mt < 2; mt++)
#pragma unroll
        for (int nt = 0; nt < 8; nt++) acc[mt][nt] = (f32x4){0, 0, 0, 0};

    // ---- layer 1 (W1 fragments from global) ----
#pragma unroll
    for (int kb = 0; kb < 4; kb++) {
        bf16x8 af[2];
#pragma unroll
        for (int mt = 0; mt < 2; mt++)
            af[mt] = *(const bf16x8*)&z[zi(w * 32 + mt * 16 + (l & 15), kb * 32 + (l >> 4) * 8)];
#pragma unroll
        for (int nt = 0; nt < 8; nt++) {
            bf16x8 wf = *(const bf16x8*)&w1p[(nt * 4 + kb) * 64 + l];
#pragma unroll
            for (int mt = 0; mt < 2; mt++)
                acc[mt][nt] = __builtin_amdgcn_mfma_f32_16x16x32_bf16(af[mt], wf, acc[mt][nt], 0, 0, 0);
        }
    }
    __syncthreads();          // all layer-1 z reads done
    // write relu(acc + b1) back to z (own rows only)
#pragma unroll
    for (int mt = 0; mt < 2; mt++)
#pragma unroll
        for (int nt = 0; nt < 8; nt++) {
            float bv = b1[16 * nt + (l & 15)];
#pragma unroll
            for (int r = 0; r < 4; r++)
                z[zi(w * 32 + mt * 16 + (l >> 4) * 4 + r, 16 * nt + (l & 15))] =
                    f2bf(fmaxf(acc[mt][nt][r] + bv, 0.0f));
        }
    __syncthreads();

    // ---- layer 2 (W2 fragments from global) ----
#pragma unroll
    for (int mt = 0; mt < 2; mt++)
#pragma unroll
        for (int nt = 0; nt < 8; nt++) acc[mt][nt] = (f32x4){0, 0, 0, 0};
#pragma unroll
    for (int kb = 0; kb < 4; kb++) {
        bf16x8 af[2];
#pragma unroll
        for (int mt = 0; mt < 2; mt++)
            af[mt] = *(const bf16x8*)&z[zi(w * 32 + mt * 16 + (l & 15), kb * 32 + (l >> 4) * 8)];
#pragma unroll
        for (int nt = 0; nt < 8; nt++) {
            bf16x8 wf = *(const bf16x8*)&w2p[(nt * 4 + kb) * 64 + l];
#pragma unroll
            for (int mt = 0; mt < 2; mt++)
                acc[mt][nt] = __builtin_amdgcn_mfma_f32_16x16x32_bf16(af[mt], wf, acc[mt][nt], 0, 0, 0);
        }
    }

    // ---- epilogue: relu(acc + b2) . W3 + b3 ----
    {
        float bb3 = b3[0];
#pragma unroll
        for (int mt = 0; mt < 2; mt++)
#pragma unroll
            for (int r = 0; r < 4; r++) {
                float p = 0.0f;
#pragma unroll
                for (int nt = 0; nt < 8; nt++)
                    p += fmaxf(acc[mt][nt][r] + b2[16 * nt + (l & 15)], 0.0f) * W3[16 * nt + (l & 15)];
                p += __shfl_xor(p, 1);
                p += __shfl_xor(p, 2);
                p += __shfl_xor(p, 4);
                p += __shfl_xor(p, 8);
                if ((l & 15) == 0)
                    out[outbase + eb + w * 32 + mt * 16 + (l >> 4) * 4 + r] = p + bb3;
            }
    }
}

// ---------------- launch ----------------
extern "C" void kernel_launch(void* const* d_in, const int* in_sizes, int n_in,
                              void* d_out, int out_size, void* d_ws, size_t ws_size,
                              hipStream_t stream) {
    const float* x    = (const float*)d_in[0];
    const int* src    = (const int*)d_in[1];
    const int* dst    = (const int*)d_in[2];
    const int* nsrc   = (const int*)d_in[3];
    const int* ndst   = (const int*)d_in[4];
    const float* W_sg = (const float*)d_in[5];
    const float* b_sg = (const float*)d_in[6];
    const float* W1   = (const float*)d_in[7];
    const float* b1   = (const float*)d_in[8];
    const float* W2   = (const float*)d_in[9];
    const float* b2   = (const float*)d_in[10];
    const float* W3   = (const float*)d_in[11];
    const float* b3   = (const float*)d_in[12];
    float* out = (float*)d_out;

    char* p = (char*)d_ws;
    float* norm = (float*)p;  p += 400000;      // NN f32
    int*   deg  = (int*)p;    p += 400000;      // NN i32
    int*   off  = (int*)p;    p += 400128;      // NN+1 i32
    int*   cur  = (int*)p;    p += 400128;      // NN+1 i32
    int*   bsum = (int*)p;    p += 512;
    int*   csr  = (int*)p;    p += 1600000;     // NE i32
    uint4* wp   = (uint4*)p;  p += 98304;
    unsigned short* xs = (unsigned short*)p;  p += (size_t)NN * FD * 2;  // 25.6 MB
    unsigned short* G1 = (unsigned short*)p;  p += (size_t)NN * FD * 2;  // 25.6 MB
    unsigned short* G2 = (unsigned short*)p;                             // 25.6 MB
    unsigned short* h  = G1;    // hop2 output overwrites G1 (dead by then)
    unsigned short* hbf = G2;   // sgconv output overwrites G2

    const int gN = (NN + 255) / 256;
    const int gE = (NE + 255) / 256;
    const int nb = (NN + SCAN_B - 1) / SCAN_B;   // 98
    const int g4 = (NN * (FD / 4) + 255) / 256;  // 12500

    k_pack_w<<<24, 256, 0, stream>>>(W_sg, W1, W2, wp);

    // ---- CSR by dst ----
    hipMemsetAsync(deg, 0, 400000, stream);
    k_deg_count<<<gE, 256, 0, stream>>>(dst, deg);
    k_scan1<<<nb, SCAN_B, 0, stream>>>(deg, off, bsum, norm);
    k_scan2<<<1, 64, 0, stream>>>(bsum, nb);
    k_scan3<<<gN, 256, 0, stream>>>(off, bsum, cur);
    k_fill<<<gE, 256, 0, stream>>>(src, dst, cur, csr);

    // ---- pre-scale + 3 propagation hops (all bf16) ----
    k_scale<<<g4, 256, 0, stream>>>(x, norm, xs);
    const int gP = NN * 32 / 256;   // 12500
    k_prop<false><<<gP, 256, 0, stream>>>(xs, off, csr, norm, G1);
    k_prop<false><<<gP, 256, 0, stream>>>(G1, off, csr, norm, G2);
    k_prop<true><<<gP, 256, 0, stream>>>(G2, off, csr, norm, h);

    // ---- SGConv linear ----
    k_sgconv_mfma<<<(NN + 127) / 128, 256, 0, stream>>>(h, wp, b_sg, hbf);

    // ---- predict MLP (pos+neg) ----
    k_predict_mfma<<<6250, 256, 0, stream>>>(hbf, src, dst, nsrc, ndst,
                                             wp + 2048, wp + 4096,
                                             b1, b2, W3, b3, out);
}

// Round 14
// 278.447 us; speedup vs baseline: 1.0634x; 1.0634x over previous
//
#include <hip/hip_runtime.h>

#define NN 100000
#define NE 400000
#define FD 128
#define SCAN_B 1024

typedef __attribute__((ext_vector_type(8))) short bf16x8;
typedef __attribute__((ext_vector_type(4))) float f32x4;

__device__ inline unsigned short f2bf(float f) {
    unsigned u = __float_as_uint(f);
    unsigned r = u + 0x7fff + ((u >> 16) & 1);
    return (unsigned short)(r >> 16);
}
__device__ inline unsigned mulbf2(unsigned a, unsigned c) {
    float a0 = __uint_as_float(a << 16), a1 = __uint_as_float(a & 0xffff0000u);
    float c0 = __uint_as_float(c << 16), c1 = __uint_as_float(c & 0xffff0000u);
    unsigned r0 = f2bf(a0 * c0);
    unsigned r1 = f2bf(a1 * c1);
    return r0 | (r1 << 16);
}
// XOR-swizzled z index (shorts), used by sgconv only. granule = 8 shorts (16B).
__device__ inline int zi(int row, int col) {
    return row * 128 + (((col >> 3) ^ (row & 7)) << 3) + (col & 7);
}

// ---------------- degree / norm / CSR ----------------
__global__ void k_deg_count(const int* __restrict__ key, int* __restrict__ deg) {
    int e = blockIdx.x * 256 + threadIdx.x;
    if (e < NE) atomicAdd(&deg[key[e]], 1);
}
// scan within 1024-blocks; also emits norm = rsqrt(deg+1)
__global__ __launch_bounds__(SCAN_B) void k_scan1(const int* __restrict__ deg,
                                                  int* __restrict__ off,
                                                  int* __restrict__ bsum,
                                                  float* __restrict__ norm) {
    __shared__ int s[SCAN_B];
    int t = threadIdx.x, g = blockIdx.x * SCAN_B + t;
    int d0 = (g < NN) ? deg[g] : 0;
    if (g < NN) norm[g] = rsqrtf((float)(d0 + 1));
    s[t] = d0;
    __syncthreads();
    for (int d = 1; d < SCAN_B; d <<= 1) {
        int add = (t >= d) ? s[t - d] : 0;
        __syncthreads();
        s[t] += add;
        __syncthreads();
    }
    if (g < NN) off[g + 1] = s[t];
    if (t == SCAN_B - 1) bsum[blockIdx.x] = s[t];
}
// wave-parallel exclusive scan of <=128 block sums (1 block, 64 threads)
__global__ void k_scan2(int* __restrict__ bsum, int nb) {
    int l = threadIdx.x;
    int v0 = (l < nb) ? bsum[l] : 0;
    int v1 = (64 + l < nb) ? bsum[64 + l] : 0;
    int a = v0;
    for (int d = 1; d < 64; d <<= 1) {
        int t = __shfl_up(a, d, 64);
        if (l >= d) a += t;
    }
    int tot0 = __shfl(a, 63, 64);
    int b = v1;
    for (int d = 1; d < 64; d <<= 1) {
        int t = __shfl_up(b, d, 64);
        if (l >= d) b += t;
    }
    if (l < nb) bsum[l] = a - v0;                 // exclusive
    if (64 + l < nb) bsum[64 + l] = tot0 + b - v1;
}
// finalize off; also emit cur = off (cursor copy)
__global__ void k_scan3(int* __restrict__ off, const int* __restrict__ bsum,
                        int* __restrict__ cur) {
    int g = blockIdx.x * 256 + threadIdx.x;
    if (g == 0) { off[0] = 0; cur[0] = 0; }
    if (g < NN) {
        int v = off[g + 1] + bsum[g / SCAN_B];
        off[g + 1] = v;
        cur[g + 1] = v;
    }
}
__global__ void k_fill(const int* __restrict__ src, const int* __restrict__ dst,
                       int* __restrict__ cur, int* __restrict__ csr) {
    int e = blockIdx.x * 256 + threadIdx.x;
    if (e < NE) {
        int p = atomicAdd(&cur[dst[e]], 1);
        csr[p] = src[e];
    }
}

// ---------------- pre-scale: xs = norm * x (bf16) ----------------
__global__ __launch_bounds__(256) void k_scale(const float* __restrict__ x,
        const float* __restrict__ norm, unsigned short* __restrict__ xs) {
    int i = blockIdx.x * 256 + threadIdx.x;   // float4 index
    if (i >= NN * (FD / 4)) return;
    int v = i >> 5;
    float nv = norm[v];
    float4 a = ((const float4*)x)[i];
    unsigned lo = f2bf(nv * a.x) | ((unsigned)f2bf(nv * a.y) << 16);
    unsigned hi = f2bf(nv * a.z) | ((unsigned)f2bf(nv * a.w) << 16);
    ((uint2*)xs)[i] = make_uint2(lo, hi);
}

// ---------------- propagation (bf16 storage, f32 accumulate) ----------------
// Gout[v] = scale * (Gin[v] + sum_s Gin[s]);  scale = nv*nv (mid) or nv (last)
template <bool LAST>
__global__ __launch_bounds__(256) void k_prop(const unsigned short* __restrict__ Gin,
        const int* __restrict__ off, const int* __restrict__ csr,
        const float* __restrict__ norm, unsigned short* __restrict__ Gout) {
    int t = blockIdx.x * 256 + threadIdx.x;
    int v = t >> 5, lane = t & 31;
    float nv = norm[v];
    uint2 g = ((const uint2*)(Gin + (size_t)v * FD))[lane];
    float ax = __uint_as_float(g.x << 16), ay = __uint_as_float(g.x & 0xffff0000u);
    float az = __uint_as_float(g.y << 16), aw = __uint_as_float(g.y & 0xffff0000u);
    int j = off[v], j1 = off[v + 1];
    for (; j + 3 < j1; j += 4) {
        int s0 = csr[j], s1 = csr[j + 1], s2 = csr[j + 2], s3 = csr[j + 3];
        uint2 b0 = ((const uint2*)(Gin + (size_t)s0 * FD))[lane];
        uint2 b1 = ((const uint2*)(Gin + (size_t)s1 * FD))[lane];
        uint2 b2 = ((const uint2*)(Gin + (size_t)s2 * FD))[lane];
        uint2 b3 = ((const uint2*)(Gin + (size_t)s3 * FD))[lane];
        ax += __uint_as_float(b0.x << 16) + __uint_as_float(b1.x << 16)
            + __uint_as_float(b2.x << 16) + __uint_as_float(b3.x << 16);
        ay += __uint_as_float(b0.x & 0xffff0000u) + __uint_as_float(b1.x & 0xffff0000u)
            + __uint_as_float(b2.x & 0xffff0000u) + __uint_as_float(b3.x & 0xffff0000u);
        az += __uint_as_float(b0.y << 16) + __uint_as_float(b1.y << 16)
            + __uint_as_float(b2.y << 16) + __uint_as_float(b3.y << 16);
        aw += __uint_as_float(b0.y & 0xffff0000u) + __uint_as_float(b1.y & 0xffff0000u)
            + __uint_as_float(b2.y & 0xffff0000u) + __uint_as_float(b3.y & 0xffff0000u);
    }
    for (; j < j1; j++) {
        int s0 = csr[j];
        uint2 b0 = ((const uint2*)(Gin + (size_t)s0 * FD))[lane];
        ax += __uint_as_float(b0.x << 16);
        ay += __uint_as_float(b0.x & 0xffff0000u);
        az += __uint_as_float(b0.y << 16);
        aw += __uint_as_float(b0.y & 0xffff0000u);
    }
    float sc = LAST ? nv : nv * nv;
    unsigned lo = f2bf(sc * ax) | ((unsigned)f2bf(sc * ay) << 16);
    unsigned hi = f2bf(sc * az) | ((unsigned)f2bf(sc * aw) << 16);
    ((uint2*)(Gout + (size_t)v * FD))[lane] = make_uint2(lo, hi);
}

// ---------------- weight packing ----------------
__global__ void k_pack_w(const float* __restrict__ Wsg, const float* __restrict__ W1,
                         const float* __restrict__ W2, uint4* __restrict__ wp) {
    int t = blockIdx.x * 256 + threadIdx.x;
    int wsel = t >> 11, r = t & 2047;
    const float* W = wsel == 0 ? Wsg : (wsel == 1 ? W1 : W2);
    int frag = r >> 6, l = r & 63;
    int nt = frag >> 2, kb = frag & 3;
    int col = 16 * nt + (l & 15);
    int k0 = 32 * kb + 8 * (l >> 4);
    unsigned q[4];
#pragma unroll
    for (int j = 0; j < 4; j++) {
        unsigned lo = f2bf(W[(size_t)(k0 + 2 * j) * FD + col]);
        unsigned hi = f2bf(W[(size_t)(k0 + 2 * j + 1) * FD + col]);
        q[j] = lo | (hi << 16);
    }
    wp[t] = make_uint4(q[0], q[1], q[2], q[3]);
}

// ---------------- SGConv linear via MFMA (32 KB swizzled LDS) ----------------
__global__ __launch_bounds__(256, 4) void k_sgconv_mfma(const unsigned short* __restrict__ hin,
        const uint4* __restrict__ wp, const float* __restrict__ bsg,
        unsigned short* __restrict__ hout) {
    __shared__ unsigned short z[128 * 128];
    int tid = threadIdx.x;
    int row0 = blockIdx.x * 128;
#pragma unroll
    for (int it = 0; it < 8; it++) {
        int idx = it * 256 + tid;
        int r = idx >> 4, c = idx & 15;
        uint4 v = make_uint4(0, 0, 0, 0);
        if (row0 + r < NN) v = *(const uint4*)(hin + (size_t)(row0 + r) * FD + c * 8);
        *(uint4*)&z[zi(r, c * 8)] = v;
    }
    __syncthreads();

    int l = tid & 63, w = tid >> 6;
    f32x4 acc[2][8];
#pragma unroll
    for (int mt = 0; mt < 2; mt++)
#pragma unroll
        for (int nt = 0; nt < 8; nt++) acc[mt][nt] = (f32x4){0, 0, 0, 0};

#pragma unroll
    for (int kb = 0; kb < 4; kb++) {
        bf16x8 af[2];
#pragma unroll
        for (int mt = 0; mt < 2; mt++)
            af[mt] = *(const bf16x8*)&z[zi(w * 32 + mt * 16 + (l & 15), kb * 32 + (l >> 4) * 8)];
#pragma unroll
        for (int nt = 0; nt < 8; nt++) {
            bf16x8 wf = *(const bf16x8*)&wp[(nt * 4 + kb) * 64 + l];
#pragma unroll
            for (int mt = 0; mt < 2; mt++)
                acc[mt][nt] = __builtin_amdgcn_mfma_f32_16x16x32_bf16(af[mt], wf, acc[mt][nt], 0, 0, 0);
        }
    }
#pragma unroll
    for (int mt = 0; mt < 2; mt++)
#pragma unroll
        for (int nt = 0; nt < 8; nt++) {
            float bv = bsg[16 * nt + (l & 15)];
#pragma unroll
            for (int r = 0; r < 4; r++)
                z[zi(w * 32 + mt * 16 + (l >> 4) * 4 + r, 16 * nt + (l & 15))] =
                    f2bf(acc[mt][nt][r] + bv);
        }
    __syncthreads();
#pragma unroll
    for (int it = 0; it < 8; it++) {
        int idx = it * 256 + tid;
        int r = idx >> 4, c = idx & 15;
        if (row0 + r < NN)
            *(uint4*)(hout + (size_t)(row0 + r) * FD + c * 8) = *(const uint4*)&z[zi(r, c * 8)];
    }
}

#define ZS 136   // z row stride in bf16 (R4/R11/R12-proven padded layout)

// ---------------- predict MLP via MFMA (pos+neg) — R12-exact ----------------
__global__ __launch_bounds__(256, 4) void k_predict_mfma(const unsigned short* __restrict__ h,
        const int* __restrict__ srcA, const int* __restrict__ dstA,
        const int* __restrict__ srcB, const int* __restrict__ dstB,
        const uint4* __restrict__ w1p, const uint4* __restrict__ w2p,
        const float* __restrict__ b1, const float* __restrict__ b2,
        const float* __restrict__ W3, const float* __restrict__ b3,
        float* __restrict__ out) {
    __shared__ unsigned short z[128 * ZS];   // 34.8 KB
    int tid = threadIdx.x;
    int b = blockIdx.x;
    int half = b >= 3125;
    int eb = (b - (half ? 3125 : 0)) * 128;
    const int* S = half ? srcB : srcA;
    const int* D = half ? dstB : dstA;
    int outbase = half ? NE : 0;

    // stage z = h[s]*h[d] (bf16); 4 threads x 64B-chunks per edge, 2 iters
#pragma unroll
    for (int it = 0; it < 2; it++) {
        int e = (tid >> 2) + 64 * it;
        int p = tid & 3;
        int s = S[eb + e], d = D[eb + e];
        const uint4* hs = (const uint4*)(h + (size_t)s * FD + p * 32);
        const uint4* hd = (const uint4*)(h + (size_t)d * FD + p * 32);
        unsigned short* zr = z + e * ZS + p * 32;
#pragma unroll
        for (int q = 0; q < 4; q++) {
            uint4 a = hs[q], c = hd[q];
            uint4 r;
            r.x = mulbf2(a.x, c.x);
            r.y = mulbf2(a.y, c.y);
            r.z = mulbf2(a.z, c.z);
            r.w = mulbf2(a.w, c.w);
            *(uint4*)(zr + q * 8) = r;
        }
    }
    __syncthreads();

    int l = tid & 63, w = tid >> 6;   // wave w owns rows w*32 .. w*32+31
    f32x4 acc[2][8];
#pragma unroll
    for (int mt = 0; mt < 2; mt++)
#pragma unroll
        for (int nt = 0; nt < 8; nt++) acc[mt][nt] = (f32x4){0, 0, 0, 0};

    // ---- layer 1 (W1 fragments from global) ----
#pragma unroll
    for (int kb = 0; kb < 4; kb++) {
        bf16x8 af[2];
#pragma unroll
        for (int mt = 0; mt < 2; mt++)
            af[mt] = *(const bf16x8*)&z[(w * 32 + mt * 16 + (l & 15)) * ZS + kb * 32 + (l >> 4) * 8];
#pragma unroll
        for (int nt = 0; nt < 8; nt++) {
            bf16x8 wf = *(const bf16x8*)&w1p[(nt * 4 + kb) * 64 + l];
#pragma unroll
            for (int mt = 0; mt < 2; mt++)
                acc[mt][nt] = __builtin_amdgcn_mfma_f32_16x16x32_bf16(af[mt], wf, acc[mt][nt], 0, 0, 0);
        }
    }
    __syncthreads();          // all layer-1 z reads done
    // write relu(acc + b1) back to z (own rows only)
#pragma unroll
    for (int mt = 0; mt < 2; mt++)
#pragma unroll
        for (int nt = 0; nt < 8; nt++) {
            float bv = b1[16 * nt + (l & 15)];
#pragma unroll
            for (int r = 0; r < 4; r++)
                z[(w * 32 + mt * 16 + (l >> 4) * 4 + r) * ZS + 16 * nt + (l & 15)] =
                    f2bf(fmaxf(acc[mt][nt][r] + bv, 0.0f));
        }
    __syncthreads();

    // ---- layer 2 (W2 fragments from global) ----
#pragma unroll
    for (int mt = 0; mt < 2; mt++)
#pragma unroll
        for (int nt = 0; nt < 8; nt++) acc[mt][nt] = (f32x4){0, 0, 0, 0};
#pragma unroll
    for (int kb = 0; kb < 4; kb++) {
        bf16x8 af[2];
#pragma unroll
        for (int mt = 0; mt < 2; mt++)
            af[mt] = *(const bf16x8*)&z[(w * 32 + mt * 16 + (l & 15)) * ZS + kb * 32 + (l >> 4) * 8];
#pragma unroll
        for (int nt = 0; nt < 8; nt++) {
            bf16x8 wf = *(const bf16x8*)&w2p[(nt * 4 + kb) * 64 + l];
#pragma unroll
            for (int mt = 0; mt < 2; mt++)
                acc[mt][nt] = __builtin_amdgcn_mfma_f32_16x16x32_bf16(af[mt], wf, acc[mt][nt], 0, 0, 0);
        }
    }

    // ---- epilogue: relu(acc + b2) . W3 + b3 ----
    {
        float bb3 = b3[0];
#pragma unroll
        for (int mt = 0; mt < 2; mt++)
#pragma unroll
            for (int r = 0; r < 4; r++) {
                float p = 0.0f;
#pragma unroll
                for (int nt = 0; nt < 8; nt++)
                    p += fmaxf(acc[mt][nt][r] + b2[16 * nt + (l & 15)], 0.0f) * W3[16 * nt + (l & 15)];
                p += __shfl_xor(p, 1);
                p += __shfl_xor(p, 2);
                p += __shfl_xor(p, 4);
                p += __shfl_xor(p, 8);
                if ((l & 15) == 0)
                    out[outbase + eb + w * 32 + mt * 16 + (l >> 4) * 4 + r] = p + bb3;
            }
    }
}

// ---------------- launch ----------------
extern "C" void kernel_launch(void* const* d_in, const int* in_sizes, int n_in,
                              void* d_out, int out_size, void* d_ws, size_t ws_size,
                              hipStream_t stream) {
    const float* x    = (const float*)d_in[0];
    const int* src    = (const int*)d_in[1];
    const int* dst    = (const int*)d_in[2];
    const int* nsrc   = (const int*)d_in[3];
    const int* ndst   = (const int*)d_in[4];
    const float* W_sg = (const float*)d_in[5];
    const float* b_sg = (const float*)d_in[6];
    const float* W1   = (const float*)d_in[7];
    const float* b1   = (const float*)d_in[8];
    const float* W2   = (const float*)d_in[9];
    const float* b2   = (const float*)d_in[10];
    const float* W3   = (const float*)d_in[11];
    const float* b3   = (const float*)d_in[12];
    float* out = (float*)d_out;

    char* p = (char*)d_ws;
    float* norm = (float*)p;  p += 400000;      // NN f32
    int*   deg  = (int*)p;    p += 400000;      // NN i32
    int*   off  = (int*)p;    p += 400128;      // NN+1 i32
    int*   cur  = (int*)p;    p += 400128;      // NN+1 i32
    int*   bsum = (int*)p;    p += 512;
    int*   csr  = (int*)p;    p += 1600000;     // NE i32
    uint4* wp   = (uint4*)p;  p += 98304;
    unsigned short* xs = (unsigned short*)p;  p += (size_t)NN * FD * 2;  // 25.6 MB
    unsigned short* G1 = (unsigned short*)p;  p += (size_t)NN * FD * 2;  // 25.6 MB
    unsigned short* G2 = (unsigned short*)p;                             // 25.6 MB
    unsigned short* h  = G1;    // hop2 output overwrites G1 (dead by then)
    unsigned short* hbf = G2;   // sgconv output overwrites G2

    const int gN = (NN + 255) / 256;
    const int gE = (NE + 255) / 256;
    const int nb = (NN + SCAN_B - 1) / SCAN_B;   // 98
    const int g4 = (NN * (FD / 4) + 255) / 256;  // 12500

    k_pack_w<<<24, 256, 0, stream>>>(W_sg, W1, W2, wp);

    // ---- CSR by dst ----
    hipMemsetAsync(deg, 0, 400000, stream);
    k_deg_count<<<gE, 256, 0, stream>>>(dst, deg);
    k_scan1<<<nb, SCAN_B, 0, stream>>>(deg, off, bsum, norm);
    k_scan2<<<1, 64, 0, stream>>>(bsum, nb);
    k_scan3<<<gN, 256, 0, stream>>>(off, bsum, cur);
    k_fill<<<gE, 256, 0, stream>>>(src, dst, cur, csr);

    // ---- pre-scale + 3 propagation hops (all bf16) ----
    k_scale<<<g4, 256, 0, stream>>>(x, norm, xs);
    const int gP = NN * 32 / 256;   // 12500
    k_prop<false><<<gP, 256, 0, stream>>>(xs, off, csr, norm, G1);
    k_prop<false><<<gP, 256, 0, stream>>>(G1, off, csr, norm, G2);
    k_prop<true><<<gP, 256, 0, stream>>>(G2, off, csr, norm, h);

    // ---- SGConv linear ----
    k_sgconv_mfma<<<(NN + 127) / 128, 256, 0, stream>>>(h, wp, b_sg, hbf);

    // ---- predict MLP (pos+neg) ----
    k_predict_mfma<<<6250, 256, 0, stream>>>(hbf, src, dst, nsrc, ndst,
                                             wp + 2048, wp + 4096,
                                             b1, b2, W3, b3, out);
}